// Round 19
// baseline (356.268 us; speedup 1.0000x reference)
//
#include <hip/hip_runtime.h>
#include <hip/hip_bf16.h>
#include <stdint.h>

// B=8, N=1024, I=256, O=256, R=8
// out[b,dst,o] = (sum_{src,r} adj[b,src,dst,r] * f[b,src,r,o]) / clip(sum adj, 1e-16)
//
//  prep : x fp32->bf16; weight -> W_t[o*8+r][i] bf16
//  k1   : f_t[b][o][k=src*8+r] = W_t @ x^T (8B vector stores)
//  k2   : R15 VERBATIM main loop (best measured: 134.3 total, k2~105):
//         MT=64 x NT=128, KS=2, 512 blocks x 512 thr (2m x 4o waves), KT=64,
//         A coalesced reg->LDS (2 sets, store kt+1), B gload_lds 4-buf kt+3,
//         counted fences vmcnt(8/4/0)+lgkmcnt(0), LDS 80KB -> 2 blocks/CU.
//         R18->R19: k3 FUSED via split-K last-block reduce: each kc-block
//         writes pout/dpart half -> __threadfence -> atomicAdd(flag[tile]);
//         second arrival fences, reads partner half, normalizes, writes out.
//         Deterministic: fp add of 2 values is commutative; flags zeroed per
//         launch by hipMemsetAsync (graph-capture-safe). Saves k3 + 24MB traffic.
//         (R15/16/17/18 established the main-loop plateau: depth+1 null,
//         LDS-25% null, A-dist+setprio regress, B-direct regress.)

typedef float          floatx4  __attribute__((ext_vector_type(4)));
typedef short          shortx8  __attribute__((ext_vector_type(8)));
typedef unsigned short ushortx4 __attribute__((ext_vector_type(4)));
typedef unsigned short ushortx8 __attribute__((ext_vector_type(8)));

__device__ __forceinline__ unsigned short f2bf(float f) {   // native RNE cast
  __hip_bfloat16 h = __float2bfloat16(f);
  unsigned short u; __builtin_memcpy(&u, &h, 2);
  return u;
}

__device__ __forceinline__ void gload16(const void* g, void* l) {
  __builtin_amdgcn_global_load_lds((__attribute__((address_space(1))) void*)g,
                                   (__attribute__((address_space(3))) void*)l,
                                   16, 0, 0);
}

// ---------------- merged prep ----------------
__global__ __launch_bounds__(256) void prep_xw(const float* __restrict__ x,
                                               const float* __restrict__ w,
                                               unsigned short* __restrict__ xbf,
                                               unsigned short* __restrict__ wt) {
  int bid = blockIdx.x;
  if (bid < 1024) {                                // x: 262144 threads x 8 elems
    int t = bid * 256 + threadIdx.x;
    const float4* p = (const float4*)x + (size_t)t * 2;
    float4 a = p[0], b4 = p[1];
    ushortx8 o;
    o[0] = f2bf(a.x);  o[1] = f2bf(a.y);  o[2] = f2bf(a.z);  o[3] = f2bf(a.w);
    o[4] = f2bf(b4.x); o[5] = f2bf(b4.y); o[6] = f2bf(b4.z); o[7] = f2bf(b4.w);
    *(ushortx8*)(xbf + (size_t)t * 8) = o;
  } else {                                         // w: 524288 scalar
    int id = (bid - 1024) * 256 + threadIdx.x;
    int r = id >> 16, i = (id >> 8) & 255, o = id & 255;
    float v = w[((size_t)(r * 256 + i) << 8) + o];
    wt[((size_t)(o * 8 + r) << 8) + i] = f2bf(v);
  }
}

// ---------------- kernel 1: f_t = x @ W (operand-swapped) ----------------
__global__ __launch_bounds__(256) void k1_gemm(const unsigned short* __restrict__ xbf,
                                               const unsigned short* __restrict__ wt,
                                               unsigned short* __restrict__ ft) {
  int bid = blockIdx.x;                            // 16 p-tiles x 64 q-tiles
  int p0 = (bid & 15) * 128, q0 = (bid >> 4) * 128;
  int l = threadIdx.x & 63, w = threadIdx.x >> 6;
  int lr = l & 15, lg = l >> 4;
  int pw = p0 + (w >> 1) * 64, qw = q0 + (w & 1) * 64;

  floatx4 acc[4][4] = {};
#pragma unroll
  for (int ks = 0; ks < 8; ++ks) {                 // K = 256 = 8 * 32
    shortx8 a[4], b[4];
#pragma unroll
    for (int pi = 0; pi < 4; ++pi)
      a[pi] = *(const shortx8*)(wt + (size_t)(pw + pi * 16 + lr) * 256 + ks * 32 + lg * 8);
#pragma unroll
    for (int qi = 0; qi < 4; ++qi)
      b[qi] = *(const shortx8*)(xbf + (size_t)(qw + qi * 16 + lr) * 256 + ks * 32 + lg * 8);
#pragma unroll
    for (int pi = 0; pi < 4; ++pi)
#pragma unroll
      for (int qi = 0; qi < 4; ++qi)
        acc[pi][qi] = __builtin_amdgcn_mfma_f32_16x16x32_bf16(a[pi], b[qi], acc[pi][qi], 0, 0, 0);
  }
  // row(n') = pw+pi*16+lg*4+reg -> (o, r); col(m) = qw+qi*16+lr -> (b8, src)
#pragma unroll
  for (int pi = 0; pi < 4; ++pi) {
    int nbase = pw + pi * 16 + lg * 4;
    int o = nbase >> 3, rb = nbase & 7;
#pragma unroll
    for (int qi = 0; qi < 4; ++qi) {
      int m = qw + qi * 16 + lr;
      int b8 = m >> 10, src = m & 1023;
      ushortx4 h;
      h[0] = f2bf(acc[pi][qi][0]); h[1] = f2bf(acc[pi][qi][1]);
      h[2] = f2bf(acc[pi][qi][2]); h[3] = f2bf(acc[pi][qi][3]);
      *(ushortx4*)(ft + ((size_t)(b8 * 256 + o) << 13) + src * 8 + rb) = h;
    }
  }
}

// ---------------- kernel 2: out = (adj^T @ f_t)/denom, split-K fused ----------------
// 512 blocks x 512 thr (8 waves, 2m x 4o). Block: b, 64 dst, 128 o, K-half.
#define ASZ 4096          // shorts per A buffer (8KB), x2
#define BSZ (128 * 64)    // shorts per B buffer (16KB), x4
__global__ __launch_bounds__(512, 4) void k2_gemm(const float* __restrict__ adj,
                                                  const unsigned short* __restrict__ ft,
                                                  float* __restrict__ pout,
                                                  float* __restrict__ dpart,
                                                  int* __restrict__ flags,
                                                  float* __restrict__ outp) {
  __shared__ __align__(16) unsigned short Alds[2 * ASZ];  // 16KB
  __shared__ __align__(16) unsigned short Blds[4 * BSZ];  // 64KB
  __shared__ int sflag;

  int bid = blockIdx.x;
  int b = bid & 7;                     // XCD pin
  int o0 = ((bid >> 3) & 1) * 128;     // 2 o-tiles
  int kc = (bid >> 4) & 1;             // split-K half
  int dst0 = (bid >> 5) * 64;          // 16 dst-tiles
  int tileid = (bid & 15) | ((bid >> 5) << 4);     // 0..255 (kc bit removed)

  int t = threadIdx.x, l = t & 63, w = t >> 6;     // 8 waves
  int lr = l & 15, lg = l >> 4;
  int wm = w >> 2, wo = w & 3;                     // wave -> (dst-half, o-quarter)

  // A-staging (coalesced): thread -> dst_l (0..63), r-half, 2 src rows (sA, sA+4)
  int dst_l = (t >> 1) & 63;
  int rh = (t & 1) * 4;
  int sA = t >> 7;                     // 0..3
  // B-staging: pre-swizzled source chunk
  int csw = (l & 7) ^ (l >> 3);

  const size_t adj_b = (size_t)b << 23;
  const unsigned short* ftb = ft + ((size_t)b << 21);
  const int src_base = kc * 512;

  float dsum = 0.f;
  floatx4 acc[2][2] = {};
  float4 avA[2], avB[2];

  auto A_load = [&](int kt, float4* v) {
#pragma unroll
    for (int j = 0; j < 2; ++j) {
      int src = src_base + kt * 8 + sA + j * 4;
      v[j] = *(const float4*)(adj + adj_b + ((size_t)src << 13)
                              + ((size_t)(dst0 + dst_l) << 3) + rh);
    }
  };
  auto A_store = [&](int abuf, const float4* v) {
#pragma unroll
    for (int j = 0; j < 2; ++j) {
      int src_l = sA + j * 4;
      float4 q = v[j];
      dsum += q.x + q.y + q.z + q.w;
      ushortx4 h;
      h[0] = f2bf(q.x); h[1] = f2bf(q.y); h[2] = f2bf(q.z); h[3] = f2bf(q.w);
      int slot = src_l ^ (dst_l & 7);
      *(ushortx4*)&Alds[abuf * ASZ + dst_l * 64 + slot * 8 + rh] = h;
    }
  };
  auto B_stage = [&](int kt, int buf) {            // 2 gload16/wave, rows w*16..+15
    int kbase = (src_base + kt * 8) * 8;
#pragma unroll
    for (int i = 0; i < 2; ++i) {
      int orow = w * 16 + i * 8 + (l >> 3);
      const unsigned short* g = ftb + ((size_t)(o0 + orow) << 13) + kbase + (csw << 3);
      gload16(g, &Blds[buf * BSZ + (w * 16 + i * 8) * 64]);
    }
  };
  auto compute = [&](int bbuf, int abuf) {
#pragma unroll
    for (int s = 0; s < 2; ++s) {
      int slotbase = s * 4 + lg;
      shortx8 af[2], bfr[2];
#pragma unroll
      for (int mi = 0; mi < 2; ++mi) {
        int arow = wm * 32 + mi * 16 + lr;
        af[mi] = *(const shortx8*)&Alds[abuf * ASZ + arow * 64 + ((slotbase ^ (arow & 7)) << 3)];
      }
#pragma unroll
      for (int ni = 0; ni < 2; ++ni) {
        int brow = wo * 32 + ni * 16 + lr;
        bfr[ni] = *(const shortx8*)&Blds[bbuf * BSZ + brow * 64 + ((slotbase ^ (brow & 7)) << 3)];
      }
#pragma unroll
      for (int mi = 0; mi < 2; ++mi)
#pragma unroll
        for (int ni = 0; ni < 2; ++ni)
          acc[mi][ni] = __builtin_amdgcn_mfma_f32_16x16x32_bf16(af[mi], bfr[ni], acc[mi][ni], 0, 0, 0);
    }
  };

// step kt: stage B(kt+3)->STG; ds_write A(kt+1) (AVx, loaded step kt-2) -> abuf ABN;
//          reload AVx with A(kt+3); compute(CUR, ABC); counted fence + barrier.
#define STEP(kt, CUR, STG, ABN, ABC, AVx, ISS, STA, FN)                \
  {                                                                    \
    if (ISS) B_stage((kt) + 3, STG);                                   \
    if (STA) A_store(ABN, AVx);                                        \
    if (ISS) A_load((kt) + 3, AVx);                                    \
    compute(CUR, ABC);                                                 \
    if (FN >= 0) {                                                     \
      __builtin_amdgcn_sched_barrier(0);                               \
      if (FN == 8)      asm volatile("s_waitcnt vmcnt(8) lgkmcnt(0)" ::: "memory"); \
      else if (FN == 4) asm volatile("s_waitcnt vmcnt(4) lgkmcnt(0)" ::: "memory"); \
      else              asm volatile("s_waitcnt vmcnt(0) lgkmcnt(0)" ::: "memory"); \
      __builtin_amdgcn_s_barrier();                                    \
      __builtin_amdgcn_sched_barrier(0);                               \
    }                                                                  \
  }

  // ---- prologue: B0,B1,B2 staged; A0 stored->abuf0; avA=A(1), avB=A(2) ----
  B_stage(0, 0);
  B_stage(1, 1);
  B_stage(2, 2);
  A_load(0, avA);
  A_store(0, avA);                     // implicit wait on A0 (prologue-only drain)
  A_load(1, avA);
  A_load(2, avB);
  asm volatile("s_waitcnt vmcnt(0) lgkmcnt(0)" ::: "memory");
  __builtin_amdgcn_s_barrier();
  __builtin_amdgcn_sched_barrier(0);

  // ---- main loop: kt 0..59, 4-step macro (buf period 4; av/abuf parity 2) ----
  for (int kt0 = 0; kt0 < 60; kt0 += 4) {
    STEP(kt0 + 0, 0, 3, 1, 0, avA, 1, 1, 8);
    STEP(kt0 + 1, 1, 0, 0, 1, avB, 1, 1, 8);
    STEP(kt0 + 2, 2, 1, 1, 0, avA, 1, 1, 8);
    STEP(kt0 + 3, 3, 2, 0, 1, avB, 1, 1, 8);
  }
  // ---- tail: kt 60..63 ----
  STEP(60, 0, 3, 1, 0, avA, 1, 1, 8);   // issues B(63)/A(63); keeps {59,60}
  STEP(61, 1, 0, 0, 1, avB, 0, 1, 4);   // stores A(62); drains batch 59
  STEP(62, 2, 0, 1, 0, avA, 0, 1, 0);   // stores A(63); drains batch 60
  STEP(63, 3, 0, 0, 1, avB, 0, 0, -1);  // compute only
#undef STEP
  __syncthreads();                     // protect Alds overlay

  // ---- denom reduction (deterministic): 8 partials per dst row ----
  float* dsf = (float*)Alds;           // [0..511] partials, [512..575] row sums
  dsf[t] = dsum;
  __syncthreads();
  if (t < 64) {
    float s = 0.f;
#pragma unroll
    for (int sl = 0; sl < 4; ++sl) {
      s += dsf[sl * 128 + t * 2];
      s += dsf[sl * 128 + t * 2 + 1];
    }
    dsf[512 + t] = s;
    dpart[kc * 8192 + (b << 10) + dst0 + t] = s;
  }
  __syncthreads();

  // ---- write my split-K partials ----
#pragma unroll
  for (int mi = 0; mi < 2; ++mi) {
#pragma unroll
    for (int reg = 0; reg < 4; ++reg) {
      int row = dst0 + wm * 32 + mi * 16 + lg * 4 + reg;
#pragma unroll
      for (int ni = 0; ni < 2; ++ni) {
        int col = o0 + wo * 32 + ni * 16 + lr;
        pout[(size_t)kc * 2097152 + (((size_t)b << 10) + row) * 256 + col] = acc[mi][ni][reg];
      }
    }
  }

  // ---- split-K rendezvous: second-arriving block reduces + normalizes ----
  __threadfence();                     // release: pout/dpart visible device-wide
  if (t == 0) sflag = atomicAdd(&flags[tileid], 1);
  __syncthreads();
  if (sflag == 1) {                    // partner already published its half
    __threadfence();                   // acquire: see partner's stores
    int kp = 1 - kc;
#pragma unroll
    for (int mi = 0; mi < 2; ++mi) {
#pragma unroll
      for (int reg = 0; reg < 4; ++reg) {
        int rl = wm * 32 + mi * 16 + lg * 4 + reg;
        int row = dst0 + rl;
        float d = dsf[512 + rl] + dpart[kp * 8192 + (b << 10) + row];
        float dinv = 1.f / fmaxf(d, 1e-16f);
#pragma unroll
        for (int ni = 0; ni < 2; ++ni) {
          int col = o0 + wo * 32 + ni * 16 + lr;
          size_t idx = (((size_t)b << 10) + row) * 256 + col;
          float v = acc[mi][ni][reg] + pout[(size_t)kp * 2097152 + idx];
          outp[idx] = v * dinv;
        }
      }
    }
  }
}

// ---------------- launch ----------------
extern "C" void kernel_launch(void* const* d_in, const int* in_sizes, int n_in,
                              void* d_out, int out_size, void* d_ws, size_t ws_size,
                              hipStream_t stream) {
  const float* x   = (const float*)d_in[0];
  const float* adj = (const float*)d_in[1];
  const float* w   = (const float*)d_in[2];
  float* out = (float*)d_out;

  char* ws = (char*)d_ws;
  unsigned short* ft  = (unsigned short*)(ws);              // 32 MB
  unsigned short* xbf = (unsigned short*)(ws + 33554432);   //  4 MB
  unsigned short* wt  = (unsigned short*)(ws + 37748736);   //  1 MB
  float* pout  = (float*)(ws + 38797312);                   // 16 MB
  float* dpart = (float*)(ws + 55574528);                   // 64 KB
  int*   flags = (int*)(ws + 55640064);                     //  1 KB

  hipMemsetAsync(flags, 0, 256 * sizeof(int), stream);      // graph-capturable
  prep_xw<<<3072, 256, 0, stream>>>(x, w, xbf, wt);
  k1_gemm<<<1024, 256, 0, stream>>>(xbf, wt, ft);
  k2_gemm<<<512, 512, 0, stream>>>(adj, ft, pout, dpart, flags, out);
}

// Round 20
// 322.418 us; speedup vs baseline: 1.1050x; 1.1050x over previous
//
#include <hip/hip_runtime.h>
#include <hip/hip_bf16.h>
#include <stdint.h>

// B=8, N=1024, I=256, O=256, R=8
// out[b,dst,o] = (sum_{src,r} adj[b,src,dst,r] * f[b,src,r,o]) / clip(sum adj, 1e-16)
//
//  prep : x fp32->bf16; weight -> W_t[o*8+r][i] bf16
//  k1   : f_t[b][o][k=src*8+r] = W_t @ x^T (8B vector stores)
//  k2   : R15-verbatim main loop (best: k2~105us) + fused split-K last-block
//         reduce (R19, proven correct). R19->R20 fix: the rendezvous flag
//         lives in the Alds overlay (dsf[576]) instead of a separate
//         __shared__ int — R19's extra 512B pushed LDS to 82432B > 80KB,
//         halving occupancy to 1 block/CU (k2 105->335us; the 4-byte/200us
//         occupancy cliff). Now LDS = exactly 81920B -> 2 blocks/CU.

typedef float          floatx4  __attribute__((ext_vector_type(4)));
typedef short          shortx8  __attribute__((ext_vector_type(8)));
typedef unsigned short ushortx4 __attribute__((ext_vector_type(4)));
typedef unsigned short ushortx8 __attribute__((ext_vector_type(8)));

__device__ __forceinline__ unsigned short f2bf(float f) {   // native RNE cast
  __hip_bfloat16 h = __float2bfloat16(f);
  unsigned short u; __builtin_memcpy(&u, &h, 2);
  return u;
}

__device__ __forceinline__ void gload16(const void* g, void* l) {
  __builtin_amdgcn_global_load_lds((__attribute__((address_space(1))) void*)g,
                                   (__attribute__((address_space(3))) void*)l,
                                   16, 0, 0);
}

// ---------------- merged prep ----------------
__global__ __launch_bounds__(256) void prep_xw(const float* __restrict__ x,
                                               const float* __restrict__ w,
                                               unsigned short* __restrict__ xbf,
                                               unsigned short* __restrict__ wt) {
  int bid = blockIdx.x;
  if (bid < 1024) {                                // x: 262144 threads x 8 elems
    int t = bid * 256 + threadIdx.x;
    const float4* p = (const float4*)x + (size_t)t * 2;
    float4 a = p[0], b4 = p[1];
    ushortx8 o;
    o[0] = f2bf(a.x);  o[1] = f2bf(a.y);  o[2] = f2bf(a.z);  o[3] = f2bf(a.w);
    o[4] = f2bf(b4.x); o[5] = f2bf(b4.y); o[6] = f2bf(b4.z); o[7] = f2bf(b4.w);
    *(ushortx8*)(xbf + (size_t)t * 8) = o;
  } else {                                         // w: 524288 scalar
    int id = (bid - 1024) * 256 + threadIdx.x;
    int r = id >> 16, i = (id >> 8) & 255, o = id & 255;
    float v = w[((size_t)(r * 256 + i) << 8) + o];
    wt[((size_t)(o * 8 + r) << 8) + i] = f2bf(v);
  }
}

// ---------------- kernel 1: f_t = x @ W (operand-swapped) ----------------
__global__ __launch_bounds__(256) void k1_gemm(const unsigned short* __restrict__ xbf,
                                               const unsigned short* __restrict__ wt,
                                               unsigned short* __restrict__ ft) {
  int bid = blockIdx.x;                            // 16 p-tiles x 64 q-tiles
  int p0 = (bid & 15) * 128, q0 = (bid >> 4) * 128;
  int l = threadIdx.x & 63, w = threadIdx.x >> 6;
  int lr = l & 15, lg = l >> 4;
  int pw = p0 + (w >> 1) * 64, qw = q0 + (w & 1) * 64;

  floatx4 acc[4][4] = {};
#pragma unroll
  for (int ks = 0; ks < 8; ++ks) {                 // K = 256 = 8 * 32
    shortx8 a[4], b[4];
#pragma unroll
    for (int pi = 0; pi < 4; ++pi)
      a[pi] = *(const shortx8*)(wt + (size_t)(pw + pi * 16 + lr) * 256 + ks * 32 + lg * 8);
#pragma unroll
    for (int qi = 0; qi < 4; ++qi)
      b[qi] = *(const shortx8*)(xbf + (size_t)(qw + qi * 16 + lr) * 256 + ks * 32 + lg * 8);
#pragma unroll
    for (int pi = 0; pi < 4; ++pi)
#pragma unroll
      for (int qi = 0; qi < 4; ++qi)
        acc[pi][qi] = __builtin_amdgcn_mfma_f32_16x16x32_bf16(a[pi], b[qi], acc[pi][qi], 0, 0, 0);
  }
  // row(n') = pw+pi*16+lg*4+reg -> (o, r); col(m) = qw+qi*16+lr -> (b8, src)
#pragma unroll
  for (int pi = 0; pi < 4; ++pi) {
    int nbase = pw + pi * 16 + lg * 4;
    int o = nbase >> 3, rb = nbase & 7;
#pragma unroll
    for (int qi = 0; qi < 4; ++qi) {
      int m = qw + qi * 16 + lr;
      int b8 = m >> 10, src = m & 1023;
      ushortx4 h;
      h[0] = f2bf(acc[pi][qi][0]); h[1] = f2bf(acc[pi][qi][1]);
      h[2] = f2bf(acc[pi][qi][2]); h[3] = f2bf(acc[pi][qi][3]);
      *(ushortx4*)(ft + ((size_t)(b8 * 256 + o) << 13) + src * 8 + rb) = h;
    }
  }
}

// ---------------- kernel 2: out = (adj^T @ f_t)/denom, split-K fused ----------------
// 512 blocks x 512 thr (8 waves, 2m x 4o). Block: b, 64 dst, 128 o, K-half.
#define ASZ 4096          // shorts per A buffer (8KB), x2
#define BSZ (128 * 64)    // shorts per B buffer (16KB), x4
__global__ __launch_bounds__(512, 4) void k2_gemm(const float* __restrict__ adj,
                                                  const unsigned short* __restrict__ ft,
                                                  float* __restrict__ pout,
                                                  float* __restrict__ dpart,
                                                  int* __restrict__ flags,
                                                  float* __restrict__ outp) {
  __shared__ __align__(16) unsigned short Alds[2 * ASZ];  // 16KB
  __shared__ __align__(16) unsigned short Blds[4 * BSZ];  // 64KB  (total exactly 80KB)

  int bid = blockIdx.x;
  int b = bid & 7;                     // XCD pin
  int o0 = ((bid >> 3) & 1) * 128;     // 2 o-tiles
  int kc = (bid >> 4) & 1;             // split-K half
  int dst0 = (bid >> 5) * 64;          // 16 dst-tiles
  int tileid = (bid & 15) | ((bid >> 5) << 4);     // 0..255 (kc bit removed)

  int t = threadIdx.x, l = t & 63, w = t >> 6;     // 8 waves
  int lr = l & 15, lg = l >> 4;
  int wm = w >> 2, wo = w & 3;                     // wave -> (dst-half, o-quarter)

  // A-staging (coalesced): thread -> dst_l (0..63), r-half, 2 src rows (sA, sA+4)
  int dst_l = (t >> 1) & 63;
  int rh = (t & 1) * 4;
  int sA = t >> 7;                     // 0..3
  // B-staging: pre-swizzled source chunk
  int csw = (l & 7) ^ (l >> 3);

  const size_t adj_b = (size_t)b << 23;
  const unsigned short* ftb = ft + ((size_t)b << 21);
  const int src_base = kc * 512;

  float dsum = 0.f;
  floatx4 acc[2][2] = {};
  float4 avA[2], avB[2];

  auto A_load = [&](int kt, float4* v) {
#pragma unroll
    for (int j = 0; j < 2; ++j) {
      int src = src_base + kt * 8 + sA + j * 4;
      v[j] = *(const float4*)(adj + adj_b + ((size_t)src << 13)
                              + ((size_t)(dst0 + dst_l) << 3) + rh);
    }
  };
  auto A_store = [&](int abuf, const float4* v) {
#pragma unroll
    for (int j = 0; j < 2; ++j) {
      int src_l = sA + j * 4;
      float4 q = v[j];
      dsum += q.x + q.y + q.z + q.w;
      ushortx4 h;
      h[0] = f2bf(q.x); h[1] = f2bf(q.y); h[2] = f2bf(q.z); h[3] = f2bf(q.w);
      int slot = src_l ^ (dst_l & 7);
      *(ushortx4*)&Alds[abuf * ASZ + dst_l * 64 + slot * 8 + rh] = h;
    }
  };
  auto B_stage = [&](int kt, int buf) {            // 2 gload16/wave, rows w*16..+15
    int kbase = (src_base + kt * 8) * 8;
#pragma unroll
    for (int i = 0; i < 2; ++i) {
      int orow = w * 16 + i * 8 + (l >> 3);
      const unsigned short* g = ftb + ((size_t)(o0 + orow) << 13) + kbase + (csw << 3);
      gload16(g, &Blds[buf * BSZ + (w * 16 + i * 8) * 64]);
    }
  };
  auto compute = [&](int bbuf, int abuf) {
#pragma unroll
    for (int s = 0; s < 2; ++s) {
      int slotbase = s * 4 + lg;
      shortx8 af[2], bfr[2];
#pragma unroll
      for (int mi = 0; mi < 2; ++mi) {
        int arow = wm * 32 + mi * 16 + lr;
        af[mi] = *(const shortx8*)&Alds[abuf * ASZ + arow * 64 + ((slotbase ^ (arow & 7)) << 3)];
      }
#pragma unroll
      for (int ni = 0; ni < 2; ++ni) {
        int brow = wo * 32 + ni * 16 + lr;
        bfr[ni] = *(const shortx8*)&Blds[bbuf * BSZ + brow * 64 + ((slotbase ^ (brow & 7)) << 3)];
      }
#pragma unroll
      for (int mi = 0; mi < 2; ++mi)
#pragma unroll
        for (int ni = 0; ni < 2; ++ni)
          acc[mi][ni] = __builtin_amdgcn_mfma_f32_16x16x32_bf16(af[mi], bfr[ni], acc[mi][ni], 0, 0, 0);
    }
  };

// step kt: stage B(kt+3)->STG; ds_write A(kt+1) (AVx, loaded step kt-2) -> abuf ABN;
//          reload AVx with A(kt+3); compute(CUR, ABC); counted fence + barrier.
#define STEP(kt, CUR, STG, ABN, ABC, AVx, ISS, STA, FN)                \
  {                                                                    \
    if (ISS) B_stage((kt) + 3, STG);                                   \
    if (STA) A_store(ABN, AVx);                                        \
    if (ISS) A_load((kt) + 3, AVx);                                    \
    compute(CUR, ABC);                                                 \
    if (FN >= 0) {                                                     \
      __builtin_amdgcn_sched_barrier(0);                               \
      if (FN == 8)      asm volatile("s_waitcnt vmcnt(8) lgkmcnt(0)" ::: "memory"); \
      else if (FN == 4) asm volatile("s_waitcnt vmcnt(4) lgkmcnt(0)" ::: "memory"); \
      else              asm volatile("s_waitcnt vmcnt(0) lgkmcnt(0)" ::: "memory"); \
      __builtin_amdgcn_s_barrier();                                    \
      __builtin_amdgcn_sched_barrier(0);                               \
    }                                                                  \
  }

  // ---- prologue: B0,B1,B2 staged; A0 stored->abuf0; avA=A(1), avB=A(2) ----
  B_stage(0, 0);
  B_stage(1, 1);
  B_stage(2, 2);
  A_load(0, avA);
  A_store(0, avA);                     // implicit wait on A0 (prologue-only drain)
  A_load(1, avA);
  A_load(2, avB);
  asm volatile("s_waitcnt vmcnt(0) lgkmcnt(0)" ::: "memory");
  __builtin_amdgcn_s_barrier();
  __builtin_amdgcn_sched_barrier(0);

  // ---- main loop: kt 0..59, 4-step macro (buf period 4; av/abuf parity 2) ----
  for (int kt0 = 0; kt0 < 60; kt0 += 4) {
    STEP(kt0 + 0, 0, 3, 1, 0, avA, 1, 1, 8);
    STEP(kt0 + 1, 1, 0, 0, 1, avB, 1, 1, 8);
    STEP(kt0 + 2, 2, 1, 1, 0, avA, 1, 1, 8);
    STEP(kt0 + 3, 3, 2, 0, 1, avB, 1, 1, 8);
  }
  // ---- tail: kt 60..63 ----
  STEP(60, 0, 3, 1, 0, avA, 1, 1, 8);   // issues B(63)/A(63); keeps {59,60}
  STEP(61, 1, 0, 0, 1, avB, 0, 1, 4);   // stores A(62); drains batch 59
  STEP(62, 2, 0, 1, 0, avA, 0, 1, 0);   // stores A(63); drains batch 60
  STEP(63, 3, 0, 0, 1, avB, 0, 0, -1);  // compute only
#undef STEP
  __syncthreads();                     // protect Alds overlay

  // ---- denom reduction (deterministic): 8 partials per dst row ----
  float* dsf = (float*)Alds;           // [0..511] partials, [512..575] sums, [576] flag
  dsf[t] = dsum;
  __syncthreads();
  if (t < 64) {
    float s = 0.f;
#pragma unroll
    for (int sl = 0; sl < 4; ++sl) {
      s += dsf[sl * 128 + t * 2];
      s += dsf[sl * 128 + t * 2 + 1];
    }
    dsf[512 + t] = s;
    dpart[kc * 8192 + (b << 10) + dst0 + t] = s;
  }
  __syncthreads();

  // ---- write my split-K partials ----
#pragma unroll
  for (int mi = 0; mi < 2; ++mi) {
#pragma unroll
    for (int reg = 0; reg < 4; ++reg) {
      int row = dst0 + wm * 32 + mi * 16 + lg * 4 + reg;
#pragma unroll
      for (int ni = 0; ni < 2; ++ni) {
        int col = o0 + wo * 32 + ni * 16 + lr;
        pout[(size_t)kc * 2097152 + (((size_t)b << 10) + row) * 256 + col] = acc[mi][ni][reg];
      }
    }
  }

  // ---- split-K rendezvous: second-arriving block reduces + normalizes ----
  __threadfence();                     // release: pout/dpart visible device-wide
  if (t == 0) ((int*)dsf)[576] = atomicAdd(&flags[tileid], 1);
  __syncthreads();
  int sflag = ((int*)dsf)[576];
  if (sflag == 1) {                    // partner already published its half
    __threadfence();                   // acquire: see partner's stores
    int kp = 1 - kc;
#pragma unroll
    for (int mi = 0; mi < 2; ++mi) {
#pragma unroll
      for (int reg = 0; reg < 4; ++reg) {
        int rl = wm * 32 + mi * 16 + lg * 4 + reg;
        int row = dst0 + rl;
        float d = dsf[512 + rl] + dpart[kp * 8192 + (b << 10) + row];
        float dinv = 1.f / fmaxf(d, 1e-16f);
#pragma unroll
        for (int ni = 0; ni < 2; ++ni) {
          int col = o0 + wo * 32 + ni * 16 + lr;
          size_t idx = (((size_t)b << 10) + row) * 256 + col;
          float v = acc[mi][ni][reg] + pout[(size_t)kp * 2097152 + idx];
          outp[idx] = v * dinv;
        }
      }
    }
  }
}

// ---------------- launch ----------------
extern "C" void kernel_launch(void* const* d_in, const int* in_sizes, int n_in,
                              void* d_out, int out_size, void* d_ws, size_t ws_size,
                              hipStream_t stream) {
  const float* x   = (const float*)d_in[0];
  const float* adj = (const float*)d_in[1];
  const float* w   = (const float*)d_in[2];
  float* out = (float*)d_out;

  char* ws = (char*)d_ws;
  unsigned short* ft  = (unsigned short*)(ws);              // 32 MB
  unsigned short* xbf = (unsigned short*)(ws + 33554432);   //  4 MB
  unsigned short* wt  = (unsigned short*)(ws + 37748736);   //  1 MB
  float* pout  = (float*)(ws + 38797312);                   // 16 MB
  float* dpart = (float*)(ws + 55574528);                   // 64 KB
  int*   flags = (int*)(ws + 55640064);                     //  1 KB

  hipMemsetAsync(flags, 0, 256 * sizeof(int), stream);      // graph-capturable
  prep_xw<<<3072, 256, 0, stream>>>(x, w, xbf, wt);
  k1_gemm<<<1024, 256, 0, stream>>>(xbf, wt, ft);
  k2_gemm<<<512, 512, 0, stream>>>(adj, ft, pout, dpart, flags, out);
}

// Round 21
// 133.789 us; speedup vs baseline: 2.6629x; 2.4099x over previous
//
#include <hip/hip_runtime.h>
#include <hip/hip_bf16.h>
#include <stdint.h>

// B=8, N=1024, I=256, O=256, R=8
// out[b,dst,o] = (sum_{src,r} adj[b,src,dst,r] * f[b,src,r,o]) / clip(sum adj, 1e-16)
//
//  prep : x fp32->bf16; weight -> W_t[o*8+r][i] bf16
//  k1   : f_t[b][o][k=src*8+r] = W_t @ x^T (8B vector stores)
//  k2   : R15 structure VERBATIM (proven best: 134.3us total, k2~105us).
//         MT=64 x NT=128, KS=2 -> 512 blocks x 512 thr (8 waves 2m x 4o), KT=64.
//         A (adj): coalesced reg-stage -> cvt -> ds_write, 2 reg sets + 2 LDS
//         bufs. B (f_t): global_load_lds, 4 buffers, issue kt+3. Counted fences
//         vmcnt(8)/4/0 + lgkmcnt(0), sched_barrier-pinned steps. LDS exactly
//         80KB -> 2 blocks/CU. Native bf16 casts. Fused fp32 denom partials.
//  k3   : sum split-K partials, normalize.
//
// Session record (why this is the consolidation point): k2 restructures all
// null/regress — depth+1 (R15 +3us), LDS-read -25% (R16 -6us), A-dist+setprio
// (R17 -35us), A-direct (R14), B-direct (R18), reg-staged-both (R9); k3-fusion
// regressed twice via codegen landmines (R19: +4B LDS -> 1 block/CU;
// R20: allocator flipped to 64 VGPR -> pipeline serialized).

typedef float          floatx4  __attribute__((ext_vector_type(4)));
typedef short          shortx8  __attribute__((ext_vector_type(8)));
typedef unsigned short ushortx4 __attribute__((ext_vector_type(4)));
typedef unsigned short ushortx8 __attribute__((ext_vector_type(8)));

__device__ __forceinline__ unsigned short f2bf(float f) {   // native RNE cast
  __hip_bfloat16 h = __float2bfloat16(f);
  unsigned short u; __builtin_memcpy(&u, &h, 2);
  return u;
}

__device__ __forceinline__ void gload16(const void* g, void* l) {
  __builtin_amdgcn_global_load_lds((__attribute__((address_space(1))) void*)g,
                                   (__attribute__((address_space(3))) void*)l,
                                   16, 0, 0);
}

// ---------------- merged prep ----------------
__global__ __launch_bounds__(256) void prep_xw(const float* __restrict__ x,
                                               const float* __restrict__ w,
                                               unsigned short* __restrict__ xbf,
                                               unsigned short* __restrict__ wt) {
  int bid = blockIdx.x;
  if (bid < 1024) {                                // x: 262144 threads x 8 elems
    int t = bid * 256 + threadIdx.x;
    const float4* p = (const float4*)x + (size_t)t * 2;
    float4 a = p[0], b4 = p[1];
    ushortx8 o;
    o[0] = f2bf(a.x);  o[1] = f2bf(a.y);  o[2] = f2bf(a.z);  o[3] = f2bf(a.w);
    o[4] = f2bf(b4.x); o[5] = f2bf(b4.y); o[6] = f2bf(b4.z); o[7] = f2bf(b4.w);
    *(ushortx8*)(xbf + (size_t)t * 8) = o;
  } else {                                         // w: 524288 scalar
    int id = (bid - 1024) * 256 + threadIdx.x;
    int r = id >> 16, i = (id >> 8) & 255, o = id & 255;
    float v = w[((size_t)(r * 256 + i) << 8) + o];
    wt[((size_t)(o * 8 + r) << 8) + i] = f2bf(v);
  }
}

// ---------------- kernel 1: f_t = x @ W (operand-swapped) ----------------
__global__ __launch_bounds__(256) void k1_gemm(const unsigned short* __restrict__ xbf,
                                               const unsigned short* __restrict__ wt,
                                               unsigned short* __restrict__ ft) {
  int bid = blockIdx.x;                            // 16 p-tiles x 64 q-tiles
  int p0 = (bid & 15) * 128, q0 = (bid >> 4) * 128;
  int l = threadIdx.x & 63, w = threadIdx.x >> 6;
  int lr = l & 15, lg = l >> 4;
  int pw = p0 + (w >> 1) * 64, qw = q0 + (w & 1) * 64;

  floatx4 acc[4][4] = {};
#pragma unroll
  for (int ks = 0; ks < 8; ++ks) {                 // K = 256 = 8 * 32
    shortx8 a[4], b[4];
#pragma unroll
    for (int pi = 0; pi < 4; ++pi)
      a[pi] = *(const shortx8*)(wt + (size_t)(pw + pi * 16 + lr) * 256 + ks * 32 + lg * 8);
#pragma unroll
    for (int qi = 0; qi < 4; ++qi)
      b[qi] = *(const shortx8*)(xbf + (size_t)(qw + qi * 16 + lr) * 256 + ks * 32 + lg * 8);
#pragma unroll
    for (int pi = 0; pi < 4; ++pi)
#pragma unroll
      for (int qi = 0; qi < 4; ++qi)
        acc[pi][qi] = __builtin_amdgcn_mfma_f32_16x16x32_bf16(a[pi], b[qi], acc[pi][qi], 0, 0, 0);
  }
  // row(n') = pw+pi*16+lg*4+reg -> (o, r); col(m) = qw+qi*16+lr -> (b8, src)
#pragma unroll
  for (int pi = 0; pi < 4; ++pi) {
    int nbase = pw + pi * 16 + lg * 4;
    int o = nbase >> 3, rb = nbase & 7;
#pragma unroll
    for (int qi = 0; qi < 4; ++qi) {
      int m = qw + qi * 16 + lr;
      int b8 = m >> 10, src = m & 1023;
      ushortx4 h;
      h[0] = f2bf(acc[pi][qi][0]); h[1] = f2bf(acc[pi][qi][1]);
      h[2] = f2bf(acc[pi][qi][2]); h[3] = f2bf(acc[pi][qi][3]);
      *(ushortx4*)(ft + ((size_t)(b8 * 256 + o) << 13) + src * 8 + rb) = h;
    }
  }
}

// ---------------- kernel 2: pout = adj^T @ f_t (+ denom) ----------------
// 512 blocks x 512 thr (8 waves, 2m x 4o). Block: b, 64 dst, 128 o, K-half.
#define ASZ 4096          // shorts per A buffer (8KB), x2
#define BSZ (128 * 64)    // shorts per B buffer (16KB), x4
__global__ __launch_bounds__(512, 4) void k2_gemm(const float* __restrict__ adj,
                                                  const unsigned short* __restrict__ ft,
                                                  float* __restrict__ pout,
                                                  float* __restrict__ dpart) {
  __shared__ __align__(16) unsigned short Alds[2 * ASZ];  // 16KB
  __shared__ __align__(16) unsigned short Blds[4 * BSZ];  // 64KB

  int bid = blockIdx.x;
  int b = bid & 7;                     // XCD pin
  int o0 = ((bid >> 3) & 1) * 128;     // 2 o-tiles
  int kc = (bid >> 4) & 1;             // split-K half
  int dst0 = (bid >> 5) * 64;          // 16 dst-tiles

  int t = threadIdx.x, l = t & 63, w = t >> 6;     // 8 waves
  int lr = l & 15, lg = l >> 4;
  int wm = w >> 2, wo = w & 3;                     // wave -> (dst-half, o-quarter)

  // A-staging (coalesced): thread -> dst_l (0..63), r-half, 2 src rows (sA, sA+4)
  int dst_l = (t >> 1) & 63;
  int rh = (t & 1) * 4;
  int sA = t >> 7;                     // 0..3
  // B-staging: pre-swizzled source chunk
  int csw = (l & 7) ^ (l >> 3);

  const size_t adj_b = (size_t)b << 23;
  const unsigned short* ftb = ft + ((size_t)b << 21);
  const int src_base = kc * 512;

  float dsum = 0.f;
  floatx4 acc[2][2] = {};
  float4 avA[2], avB[2];

  auto A_load = [&](int kt, float4* v) {
#pragma unroll
    for (int j = 0; j < 2; ++j) {
      int src = src_base + kt * 8 + sA + j * 4;
      v[j] = *(const float4*)(adj + adj_b + ((size_t)src << 13)
                              + ((size_t)(dst0 + dst_l) << 3) + rh);
    }
  };
  auto A_store = [&](int abuf, const float4* v) {
#pragma unroll
    for (int j = 0; j < 2; ++j) {
      int src_l = sA + j * 4;
      float4 q = v[j];
      dsum += q.x + q.y + q.z + q.w;
      ushortx4 h;
      h[0] = f2bf(q.x); h[1] = f2bf(q.y); h[2] = f2bf(q.z); h[3] = f2bf(q.w);
      int slot = src_l ^ (dst_l & 7);
      *(ushortx4*)&Alds[abuf * ASZ + dst_l * 64 + slot * 8 + rh] = h;
    }
  };
  auto B_stage = [&](int kt, int buf) {            // 2 gload16/wave, rows w*16..+15
    int kbase = (src_base + kt * 8) * 8;
#pragma unroll
    for (int i = 0; i < 2; ++i) {
      int orow = w * 16 + i * 8 + (l >> 3);
      const unsigned short* g = ftb + ((size_t)(o0 + orow) << 13) + kbase + (csw << 3);
      gload16(g, &Blds[buf * BSZ + (w * 16 + i * 8) * 64]);
    }
  };
  auto compute = [&](int bbuf, int abuf) {
#pragma unroll
    for (int s = 0; s < 2; ++s) {
      int slotbase = s * 4 + lg;
      shortx8 af[2], bfr[2];
#pragma unroll
      for (int mi = 0; mi < 2; ++mi) {
        int arow = wm * 32 + mi * 16 + lr;
        af[mi] = *(const shortx8*)&Alds[abuf * ASZ + arow * 64 + ((slotbase ^ (arow & 7)) << 3)];
      }
#pragma unroll
      for (int ni = 0; ni < 2; ++ni) {
        int brow = wo * 32 + ni * 16 + lr;
        bfr[ni] = *(const shortx8*)&Blds[bbuf * BSZ + brow * 64 + ((slotbase ^ (brow & 7)) << 3)];
      }
#pragma unroll
      for (int mi = 0; mi < 2; ++mi)
#pragma unroll
        for (int ni = 0; ni < 2; ++ni)
          acc[mi][ni] = __builtin_amdgcn_mfma_f32_16x16x32_bf16(af[mi], bfr[ni], acc[mi][ni], 0, 0, 0);
    }
  };

// step kt: stage B(kt+3)->STG; ds_write A(kt+1) (AVx, loaded step kt-2) -> abuf ABN;
//          reload AVx with A(kt+3); compute(CUR, ABC); counted fence + barrier.
#define STEP(kt, CUR, STG, ABN, ABC, AVx, ISS, STA, FN)                \
  {                                                                    \
    if (ISS) B_stage((kt) + 3, STG);                                   \
    if (STA) A_store(ABN, AVx);                                        \
    if (ISS) A_load((kt) + 3, AVx);                                    \
    compute(CUR, ABC);                                                 \
    if (FN >= 0) {                                                     \
      __builtin_amdgcn_sched_barrier(0);                               \
      if (FN == 8)      asm volatile("s_waitcnt vmcnt(8) lgkmcnt(0)" ::: "memory"); \
      else if (FN == 4) asm volatile("s_waitcnt vmcnt(4) lgkmcnt(0)" ::: "memory"); \
      else              asm volatile("s_waitcnt vmcnt(0) lgkmcnt(0)" ::: "memory"); \
      __builtin_amdgcn_s_barrier();                                    \
      __builtin_amdgcn_sched_barrier(0);                               \
    }                                                                  \
  }

  // ---- prologue: B0,B1,B2 staged; A0 stored->abuf0; avA=A(1), avB=A(2) ----
  B_stage(0, 0);
  B_stage(1, 1);
  B_stage(2, 2);
  A_load(0, avA);
  A_store(0, avA);                     // implicit wait on A0 (prologue-only drain)
  A_load(1, avA);
  A_load(2, avB);
  asm volatile("s_waitcnt vmcnt(0) lgkmcnt(0)" ::: "memory");
  __builtin_amdgcn_s_barrier();
  __builtin_amdgcn_sched_barrier(0);

  // ---- main loop: kt 0..59, 4-step macro (buf period 4; av/abuf parity 2) ----
  for (int kt0 = 0; kt0 < 60; kt0 += 4) {
    STEP(kt0 + 0, 0, 3, 1, 0, avA, 1, 1, 8);
    STEP(kt0 + 1, 1, 0, 0, 1, avB, 1, 1, 8);
    STEP(kt0 + 2, 2, 1, 1, 0, avA, 1, 1, 8);
    STEP(kt0 + 3, 3, 2, 0, 1, avB, 1, 1, 8);
  }
  // ---- tail: kt 60..63 ----
  STEP(60, 0, 3, 1, 0, avA, 1, 1, 8);   // issues B(63)/A(63); keeps {59,60}
  STEP(61, 1, 0, 0, 1, avB, 0, 1, 4);   // stores A(62); drains batch 59
  STEP(62, 2, 0, 1, 0, avA, 0, 1, 0);   // stores A(63); drains batch 60
  STEP(63, 3, 0, 0, 1, avB, 0, 0, -1);  // compute only
#undef STEP
  __syncthreads();                     // protect Alds overlay

  // ---- denom reduction (deterministic): 8 partials per dst row ----
  float* dsf = (float*)Alds;
  dsf[t] = dsum;
  __syncthreads();
  if (t < 64) {
    float s = 0.f;
#pragma unroll
    for (int sl = 0; sl < 4; ++sl) {
      s += dsf[sl * 128 + t * 2];
      s += dsf[sl * 128 + t * 2 + 1];
    }
    dpart[kc * 8192 + (b << 10) + dst0 + t] = s;
  }

  // ---- write partials ----
#pragma unroll
  for (int mi = 0; mi < 2; ++mi) {
#pragma unroll
    for (int reg = 0; reg < 4; ++reg) {
      int row = dst0 + wm * 32 + mi * 16 + lg * 4 + reg;
#pragma unroll
      for (int ni = 0; ni < 2; ++ni) {
        int col = o0 + wo * 32 + ni * 16 + lr;
        pout[(size_t)kc * 2097152 + (((size_t)b << 10) + row) * 256 + col] = acc[mi][ni][reg];
      }
    }
  }
}

// ---------------- kernel 3: split-K reduce + normalize ----------------
__global__ __launch_bounds__(256) void k3_reduce(const float* __restrict__ pout,
                                                 const float* __restrict__ dpart,
                                                 float* __restrict__ outp) {
  int bid = blockIdx.x;              // b*1024 + dst
  size_t base = (size_t)bid * 256 + threadIdx.x;
  float v = pout[base] + pout[2097152 + base];
  float d = dpart[bid] + dpart[8192 + bid];
  outp[base] = v / fmaxf(d, 1e-16f);
}

// ---------------- launch ----------------
extern "C" void kernel_launch(void* const* d_in, const int* in_sizes, int n_in,
                              void* d_out, int out_size, void* d_ws, size_t ws_size,
                              hipStream_t stream) {
  const float* x   = (const float*)d_in[0];
  const float* adj = (const float*)d_in[1];
  const float* w   = (const float*)d_in[2];
  float* out = (float*)d_out;

  char* ws = (char*)d_ws;
  unsigned short* ft  = (unsigned short*)(ws);              // 32 MB
  unsigned short* xbf = (unsigned short*)(ws + 33554432);   //  4 MB
  unsigned short* wt  = (unsigned short*)(ws + 37748736);   //  1 MB
  float* pout  = (float*)(ws + 38797312);                   // 16 MB
  float* dpart = (float*)(ws + 55574528);                   // 64 KB

  prep_xw<<<3072, 256, 0, stream>>>(x, w, xbf, wt);
  k1_gemm<<<1024, 256, 0, stream>>>(xbf, wt, ft);
  k2_gemm<<<512, 512, 0, stream>>>(adj, ft, pout, dpart);
  k3_reduce<<<8192, 256, 0, stream>>>(pout, dpart, out);
}

// Round 22
// 133.677 us; speedup vs baseline: 2.6651x; 1.0008x over previous
//
#include <hip/hip_runtime.h>
#include <hip/hip_bf16.h>
#include <stdint.h>

// B=8, N=1024, I=256, O=256, R=8
// out[b,dst,o] = (sum_{src,r} adj[b,src,dst,r] * f[b,src,r,o]) / clip(sum adj, 1e-16)
//
//  prep : x fp32->bf16; weight -> W_t[o*8+r][i] bf16
//  k1   : f_t[b][o][k=src*8+r] = W_t @ x^T (8B vector stores)
//  k2   : R15 structure VERBATIM (proven best; k2~105us).
//  k3   : split-K reduce + normalize, float4-vectorized (2048 blocks).
//
// Plateau record: k2's per-CU barrier-round count is LDS-locked at ~64
// (pairing kt needs 96-128KB -> 1 blk/CU; smaller tiles double block count ->
// rounds re-serialize at the 2/CU LDS cap). Six restructures null/regress;
// two k3-fusions hit codegen landmines (R19 +4B LDS cliff, R20 VGPR=64 flip).
// R21 consolidated at 133.8us. This round: only the safe k3 float4 polish.

typedef float          floatx4  __attribute__((ext_vector_type(4)));
typedef short          shortx8  __attribute__((ext_vector_type(8)));
typedef unsigned short ushortx4 __attribute__((ext_vector_type(4)));
typedef unsigned short ushortx8 __attribute__((ext_vector_type(8)));

__device__ __forceinline__ unsigned short f2bf(float f) {   // native RNE cast
  __hip_bfloat16 h = __float2bfloat16(f);
  unsigned short u; __builtin_memcpy(&u, &h, 2);
  return u;
}

__device__ __forceinline__ void gload16(const void* g, void* l) {
  __builtin_amdgcn_global_load_lds((__attribute__((address_space(1))) void*)g,
                                   (__attribute__((address_space(3))) void*)l,
                                   16, 0, 0);
}

// ---------------- merged prep ----------------
__global__ __launch_bounds__(256) void prep_xw(const float* __restrict__ x,
                                               const float* __restrict__ w,
                                               unsigned short* __restrict__ xbf,
                                               unsigned short* __restrict__ wt) {
  int bid = blockIdx.x;
  if (bid < 1024) {                                // x: 262144 threads x 8 elems
    int t = bid * 256 + threadIdx.x;
    const float4* p = (const float4*)x + (size_t)t * 2;
    float4 a = p[0], b4 = p[1];
    ushortx8 o;
    o[0] = f2bf(a.x);  o[1] = f2bf(a.y);  o[2] = f2bf(a.z);  o[3] = f2bf(a.w);
    o[4] = f2bf(b4.x); o[5] = f2bf(b4.y); o[6] = f2bf(b4.z); o[7] = f2bf(b4.w);
    *(ushortx8*)(xbf + (size_t)t * 8) = o;
  } else {                                         // w: 524288 scalar
    int id = (bid - 1024) * 256 + threadIdx.x;
    int r = id >> 16, i = (id >> 8) & 255, o = id & 255;
    float v = w[((size_t)(r * 256 + i) << 8) + o];
    wt[((size_t)(o * 8 + r) << 8) + i] = f2bf(v);
  }
}

// ---------------- kernel 1: f_t = x @ W (operand-swapped) ----------------
__global__ __launch_bounds__(256) void k1_gemm(const unsigned short* __restrict__ xbf,
                                               const unsigned short* __restrict__ wt,
                                               unsigned short* __restrict__ ft) {
  int bid = blockIdx.x;                            // 16 p-tiles x 64 q-tiles
  int p0 = (bid & 15) * 128, q0 = (bid >> 4) * 128;
  int l = threadIdx.x & 63, w = threadIdx.x >> 6;
  int lr = l & 15, lg = l >> 4;
  int pw = p0 + (w >> 1) * 64, qw = q0 + (w & 1) * 64;

  floatx4 acc[4][4] = {};
#pragma unroll
  for (int ks = 0; ks < 8; ++ks) {                 // K = 256 = 8 * 32
    shortx8 a[4], b[4];
#pragma unroll
    for (int pi = 0; pi < 4; ++pi)
      a[pi] = *(const shortx8*)(wt + (size_t)(pw + pi * 16 + lr) * 256 + ks * 32 + lg * 8);
#pragma unroll
    for (int qi = 0; qi < 4; ++qi)
      b[qi] = *(const shortx8*)(xbf + (size_t)(qw + qi * 16 + lr) * 256 + ks * 32 + lg * 8);
#pragma unroll
    for (int pi = 0; pi < 4; ++pi)
#pragma unroll
      for (int qi = 0; qi < 4; ++qi)
        acc[pi][qi] = __builtin_amdgcn_mfma_f32_16x16x32_bf16(a[pi], b[qi], acc[pi][qi], 0, 0, 0);
  }
  // row(n') = pw+pi*16+lg*4+reg -> (o, r); col(m) = qw+qi*16+lr -> (b8, src)
#pragma unroll
  for (int pi = 0; pi < 4; ++pi) {
    int nbase = pw + pi * 16 + lg * 4;
    int o = nbase >> 3, rb = nbase & 7;
#pragma unroll
    for (int qi = 0; qi < 4; ++qi) {
      int m = qw + qi * 16 + lr;
      int b8 = m >> 10, src = m & 1023;
      ushortx4 h;
      h[0] = f2bf(acc[pi][qi][0]); h[1] = f2bf(acc[pi][qi][1]);
      h[2] = f2bf(acc[pi][qi][2]); h[3] = f2bf(acc[pi][qi][3]);
      *(ushortx4*)(ft + ((size_t)(b8 * 256 + o) << 13) + src * 8 + rb) = h;
    }
  }
}

// ---------------- kernel 2: pout = adj^T @ f_t (+ denom) ----------------
// 512 blocks x 512 thr (8 waves, 2m x 4o). Block: b, 64 dst, 128 o, K-half.
#define ASZ 4096          // shorts per A buffer (8KB), x2
#define BSZ (128 * 64)    // shorts per B buffer (16KB), x4
__global__ __launch_bounds__(512, 4) void k2_gemm(const float* __restrict__ adj,
                                                  const unsigned short* __restrict__ ft,
                                                  float* __restrict__ pout,
                                                  float* __restrict__ dpart) {
  __shared__ __align__(16) unsigned short Alds[2 * ASZ];  // 16KB
  __shared__ __align__(16) unsigned short Blds[4 * BSZ];  // 64KB

  int bid = blockIdx.x;
  int b = bid & 7;                     // XCD pin
  int o0 = ((bid >> 3) & 1) * 128;     // 2 o-tiles
  int kc = (bid >> 4) & 1;             // split-K half
  int dst0 = (bid >> 5) * 64;          // 16 dst-tiles

  int t = threadIdx.x, l = t & 63, w = t >> 6;     // 8 waves
  int lr = l & 15, lg = l >> 4;
  int wm = w >> 2, wo = w & 3;                     // wave -> (dst-half, o-quarter)

  // A-staging (coalesced): thread -> dst_l (0..63), r-half, 2 src rows (sA, sA+4)
  int dst_l = (t >> 1) & 63;
  int rh = (t & 1) * 4;
  int sA = t >> 7;                     // 0..3
  // B-staging: pre-swizzled source chunk
  int csw = (l & 7) ^ (l >> 3);

  const size_t adj_b = (size_t)b << 23;
  const unsigned short* ftb = ft + ((size_t)b << 21);
  const int src_base = kc * 512;

  float dsum = 0.f;
  floatx4 acc[2][2] = {};
  float4 avA[2], avB[2];

  auto A_load = [&](int kt, float4* v) {
#pragma unroll
    for (int j = 0; j < 2; ++j) {
      int src = src_base + kt * 8 + sA + j * 4;
      v[j] = *(const float4*)(adj + adj_b + ((size_t)src << 13)
                              + ((size_t)(dst0 + dst_l) << 3) + rh);
    }
  };
  auto A_store = [&](int abuf, const float4* v) {
#pragma unroll
    for (int j = 0; j < 2; ++j) {
      int src_l = sA + j * 4;
      float4 q = v[j];
      dsum += q.x + q.y + q.z + q.w;
      ushortx4 h;
      h[0] = f2bf(q.x); h[1] = f2bf(q.y); h[2] = f2bf(q.z); h[3] = f2bf(q.w);
      int slot = src_l ^ (dst_l & 7);
      *(ushortx4*)&Alds[abuf * ASZ + dst_l * 64 + slot * 8 + rh] = h;
    }
  };
  auto B_stage = [&](int kt, int buf) {            // 2 gload16/wave, rows w*16..+15
    int kbase = (src_base + kt * 8) * 8;
#pragma unroll
    for (int i = 0; i < 2; ++i) {
      int orow = w * 16 + i * 8 + (l >> 3);
      const unsigned short* g = ftb + ((size_t)(o0 + orow) << 13) + kbase + (csw << 3);
      gload16(g, &Blds[buf * BSZ + (w * 16 + i * 8) * 64]);
    }
  };
  auto compute = [&](int bbuf, int abuf) {
#pragma unroll
    for (int s = 0; s < 2; ++s) {
      int slotbase = s * 4 + lg;
      shortx8 af[2], bfr[2];
#pragma unroll
      for (int mi = 0; mi < 2; ++mi) {
        int arow = wm * 32 + mi * 16 + lr;
        af[mi] = *(const shortx8*)&Alds[abuf * ASZ + arow * 64 + ((slotbase ^ (arow & 7)) << 3)];
      }
#pragma unroll
      for (int ni = 0; ni < 2; ++ni) {
        int brow = wo * 32 + ni * 16 + lr;
        bfr[ni] = *(const shortx8*)&Blds[bbuf * BSZ + brow * 64 + ((slotbase ^ (brow & 7)) << 3)];
      }
#pragma unroll
      for (int mi = 0; mi < 2; ++mi)
#pragma unroll
        for (int ni = 0; ni < 2; ++ni)
          acc[mi][ni] = __builtin_amdgcn_mfma_f32_16x16x32_bf16(af[mi], bfr[ni], acc[mi][ni], 0, 0, 0);
    }
  };

// step kt: stage B(kt+3)->STG; ds_write A(kt+1) (AVx, loaded step kt-2) -> abuf ABN;
//          reload AVx with A(kt+3); compute(CUR, ABC); counted fence + barrier.
#define STEP(kt, CUR, STG, ABN, ABC, AVx, ISS, STA, FN)                \
  {                                                                    \
    if (ISS) B_stage((kt) + 3, STG);                                   \
    if (STA) A_store(ABN, AVx);                                        \
    if (ISS) A_load((kt) + 3, AVx);                                    \
    compute(CUR, ABC);                                                 \
    if (FN >= 0) {                                                     \
      __builtin_amdgcn_sched_barrier(0);                               \
      if (FN == 8)      asm volatile("s_waitcnt vmcnt(8) lgkmcnt(0)" ::: "memory"); \
      else if (FN == 4) asm volatile("s_waitcnt vmcnt(4) lgkmcnt(0)" ::: "memory"); \
      else              asm volatile("s_waitcnt vmcnt(0) lgkmcnt(0)" ::: "memory"); \
      __builtin_amdgcn_s_barrier();                                    \
      __builtin_amdgcn_sched_barrier(0);                               \
    }                                                                  \
  }

  // ---- prologue: B0,B1,B2 staged; A0 stored->abuf0; avA=A(1), avB=A(2) ----
  B_stage(0, 0);
  B_stage(1, 1);
  B_stage(2, 2);
  A_load(0, avA);
  A_store(0, avA);                     // implicit wait on A0 (prologue-only drain)
  A_load(1, avA);
  A_load(2, avB);
  asm volatile("s_waitcnt vmcnt(0) lgkmcnt(0)" ::: "memory");
  __builtin_amdgcn_s_barrier();
  __builtin_amdgcn_sched_barrier(0);

  // ---- main loop: kt 0..59, 4-step macro (buf period 4; av/abuf parity 2) ----
  for (int kt0 = 0; kt0 < 60; kt0 += 4) {
    STEP(kt0 + 0, 0, 3, 1, 0, avA, 1, 1, 8);
    STEP(kt0 + 1, 1, 0, 0, 1, avB, 1, 1, 8);
    STEP(kt0 + 2, 2, 1, 1, 0, avA, 1, 1, 8);
    STEP(kt0 + 3, 3, 2, 0, 1, avB, 1, 1, 8);
  }
  // ---- tail: kt 60..63 ----
  STEP(60, 0, 3, 1, 0, avA, 1, 1, 8);   // issues B(63)/A(63); keeps {59,60}
  STEP(61, 1, 0, 0, 1, avB, 0, 1, 4);   // stores A(62); drains batch 59
  STEP(62, 2, 0, 1, 0, avA, 0, 1, 0);   // stores A(63); drains batch 60
  STEP(63, 3, 0, 0, 1, avB, 0, 0, -1);  // compute only
#undef STEP
  __syncthreads();                     // protect Alds overlay

  // ---- denom reduction (deterministic): 8 partials per dst row ----
  float* dsf = (float*)Alds;
  dsf[t] = dsum;
  __syncthreads();
  if (t < 64) {
    float s = 0.f;
#pragma unroll
    for (int sl = 0; sl < 4; ++sl) {
      s += dsf[sl * 128 + t * 2];
      s += dsf[sl * 128 + t * 2 + 1];
    }
    dpart[kc * 8192 + (b << 10) + dst0 + t] = s;
  }

  // ---- write partials ----
#pragma unroll
  for (int mi = 0; mi < 2; ++mi) {
#pragma unroll
    for (int reg = 0; reg < 4; ++reg) {
      int row = dst0 + wm * 32 + mi * 16 + lg * 4 + reg;
#pragma unroll
      for (int ni = 0; ni < 2; ++ni) {
        int col = o0 + wo * 32 + ni * 16 + lr;
        pout[(size_t)kc * 2097152 + (((size_t)b << 10) + row) * 256 + col] = acc[mi][ni][reg];
      }
    }
  }
}

// ---------------- kernel 3: split-K reduce + normalize (float4) ----------------
// 2048 blocks x 256 thr x 4 elems. Each 64-thread group covers one dst row.
__global__ __launch_bounds__(256) void k3_reduce(const float* __restrict__ pout,
                                                 const float* __restrict__ dpart,
                                                 float* __restrict__ outp) {
  size_t e4 = (size_t)blockIdx.x * 256 + threadIdx.x;   // float4 index
  int row = (int)(e4 >> 6);                             // (b*1024+dst), 64 float4/row
  float4 v0 = *((const float4*)pout + e4);
  float4 v1 = *((const float4*)(pout + 2097152) + e4);
  float d = dpart[row] + dpart[8192 + row];
  float dinv = 1.f / fmaxf(d, 1e-16f);
  float4 r;
  r.x = (v0.x + v1.x) * dinv;
  r.y = (v0.y + v1.y) * dinv;
  r.z = (v0.z + v1.z) * dinv;
  r.w = (v0.w + v1.w) * dinv;
  *((float4*)outp + e4) = r;
}

// ---------------- launch ----------------
extern "C" void kernel_launch(void* const* d_in, const int* in_sizes, int n_in,
                              void* d_out, int out_size, void* d_ws, size_t ws_size,
                              hipStream_t stream) {
  const float* x   = (const float*)d_in[0];
  const float* adj = (const float*)d_in[1];
  const float* w   = (const float*)d_in[2];
  float* out = (float*)d_out;

  char* ws = (char*)d_ws;
  unsigned short* ft  = (unsigned short*)(ws);              // 32 MB
  unsigned short* xbf = (unsigned short*)(ws + 33554432);   //  4 MB
  unsigned short* wt  = (unsigned short*)(ws + 37748736);   //  1 MB
  float* pout  = (float*)(ws + 38797312);                   // 16 MB
  float* dpart = (float*)(ws + 55574528);                   // 64 KB

  prep_xw<<<3072, 256, 0, stream>>>(x, w, xbf, wt);
  k1_gemm<<<1024, 256, 0, stream>>>(xbf, wt, ft);
  k2_gemm<<<512, 512, 0, stream>>>(adj, ft, pout, dpart);
  k3_reduce<<<2048, 256, 0, stream>>>(pout, dpart, out);
}